// Round 1
// baseline (639.094 us; speedup 1.0000x reference)
//
#include <hip/hip_runtime.h>
#include <math.h>

#define N_TOT 160000
#define NL0   100000
#define NL1   60000
#define NBOX  128
#define FMAXV 1e8f

// ws float offsets
#define WS_SUM 0
#define WS_SQ  128
#define WS_S   256
#define WS_T   384
#define WS_T4  512
#define WS_WH  1024
#define WS_BH  2176
#define WS_KTH 2192

// ---------------- prep: zero stats, T4 = text@Wf[128:]+b_fuse, pack head weights ----------------
__global__ void prep_kernel(const float* __restrict__ text, const float* __restrict__ Wf,
                            const float* __restrict__ bfuse, const float* __restrict__ Wbbox,
                            const float* __restrict__ bbbox, const float* __restrict__ Wcls,
                            const float* __restrict__ bcls, float* __restrict__ ws)
{
    int t = threadIdx.x;
    if (t < 128) { ws[WS_SUM + t] = 0.f; ws[WS_SQ + t] = 0.f; }
    for (int idx = t; idx < 512; idx += 256) {
        int b = idx >> 7, c = idx & 127;
        float acc = bfuse[c];
        for (int k = 0; k < 128; ++k) acc += text[b * 128 + k] * Wf[(128 + k) * 128 + c];
        ws[WS_T4 + idx] = acc;
    }
    for (int idx = t; idx < 1152; idx += 256) {
        int k = idx / 9, j = idx - k * 9;
        ws[WS_WH + idx] = (j < 7) ? Wbbox[k * 7 + j] : Wcls[k * 2 + (j - 7)];
    }
    if (t < 9) ws[WS_BH + t] = (t < 7) ? bbbox[t] : bcls[t - 7];
}

// ---------------- GEMM core: 64 rows/block, 256 thr: tx=col/4, ty=rowgrp ----------------
// acc[i][j]: rows r0+ty*8+i, cols tx*4+j. W staged in LDS in two 64-row K phases.
#define GEMM_BODY(A, Wf, lw, acc, r0, tx, ty, c0)                                        \
    for (int ph = 0; ph < 2; ++ph) {                                                     \
        const float4* wsrc = (const float4*)((Wf) + ph * 8192);                          \
        float4* wdst = (float4*)(lw);                                                    \
        for (int i = threadIdx.x; i < 2048; i += 256) wdst[i] = wsrc[i];                 \
        __syncthreads();                                                                 \
        for (int k4 = 0; k4 < 16; ++k4) {                                                \
            float4 a[8];                                                                 \
            _Pragma("unroll")                                                            \
            for (int i = 0; i < 8; ++i)                                                  \
                a[i] = *(const float4*)((A) + (size_t)((r0) + (ty) * 8 + i) * 128 + ph * 64 + k4 * 4); \
            _Pragma("unroll")                                                            \
            for (int kk = 0; kk < 4; ++kk) {                                             \
                float4 w = *(const float4*)((lw) + (k4 * 4 + kk) * 128 + (c0));          \
                _Pragma("unroll")                                                        \
                for (int i = 0; i < 8; ++i) {                                            \
                    float av = (kk == 0) ? a[i].x : (kk == 1) ? a[i].y : (kk == 2) ? a[i].z : a[i].w; \
                    acc[i][0] += av * w.x; acc[i][1] += av * w.y;                        \
                    acc[i][2] += av * w.z; acc[i][3] += av * w.w;                        \
                }                                                                        \
            }                                                                            \
        }                                                                                \
        __syncthreads();                                                                 \
    }

__global__ __launch_bounds__(256) void gemm_stats_kernel(const float* __restrict__ A,
                                                         const float* __restrict__ Wf,
                                                         const int* __restrict__ bidx,
                                                         float* __restrict__ ws)
{
    __shared__ float lw[8192];
    __shared__ float red[2048];
    const int tid = threadIdx.x;
    const int tx = tid & 31, ty = tid >> 5;
    const int r0 = blockIdx.x * 64;
    const int c0 = tx * 4;
    float acc[8][4];
#pragma unroll
    for (int i = 0; i < 8; ++i)
#pragma unroll
        for (int j = 0; j < 4; ++j) acc[i][j] = 0.f;

    GEMM_BODY(A, Wf, lw, acc, r0, tx, ty, c0)

    const float* T4 = ws + WS_T4;
#pragma unroll
    for (int i = 0; i < 8; ++i) {
        int r = r0 + ty * 8 + i;
        int b = bidx[r];
        float4 tv = *(const float4*)(T4 + b * 128 + c0);
        acc[i][0] += tv.x; acc[i][1] += tv.y; acc[i][2] += tv.z; acc[i][3] += tv.w;
    }
#pragma unroll
    for (int j = 0; j < 4; ++j) {
        float s = 0.f, s2 = 0.f;
#pragma unroll
        for (int i = 0; i < 8; ++i) { float v = acc[i][j]; s += v; s2 += v * v; }
        red[(c0 + j) * 8 + ty] = s;
        red[1024 + (c0 + j) * 8 + ty] = s2;
    }
    __syncthreads();
    if (tid < 128) {
        float s = 0.f, s2 = 0.f;
#pragma unroll
        for (int u = 0; u < 8; ++u) { s += red[tid * 8 + u]; s2 += red[1024 + tid * 8 + u]; }
        atomicAdd(ws + WS_SUM + tid, s);
        atomicAdd(ws + WS_SQ + tid, s2);
    }
}

__global__ void finalize_kernel(const float* __restrict__ gamma, const float* __restrict__ beta,
                                float* __restrict__ ws, int n)
{
    int c = threadIdx.x;
    if (c < 128) {
        float inv_n = 1.f / (float)n;
        float mu  = ws[WS_SUM + c] * inv_n;
        float var = ws[WS_SQ + c] * inv_n - mu * mu;
        float s = gamma[c] / sqrtf(var + 1e-5f);
        ws[WS_S + c] = s;
        ws[WS_T + c] = beta[c] - mu * s;
    }
}

__global__ __launch_bounds__(256) void heads_kernel(const float* __restrict__ A,
                                                    const float* __restrict__ Wf,
                                                    const int* __restrict__ bidx,
                                                    const float* __restrict__ ws,
                                                    float* __restrict__ out)
{
    __shared__ float lw[8192];
    const int tid = threadIdx.x;
    const int tx = tid & 31, ty = tid >> 5;
    const int r0 = blockIdx.x * 64;
    const int c0 = tx * 4;
    float acc[8][4];
#pragma unroll
    for (int i = 0; i < 8; ++i)
#pragma unroll
        for (int j = 0; j < 4; ++j) acc[i][j] = 0.f;

    GEMM_BODY(A, Wf, lw, acc, r0, tx, ty, c0)

    const float* T4 = ws + WS_T4;
#pragma unroll
    for (int i = 0; i < 8; ++i) {
        int r = r0 + ty * 8 + i;
        int b = bidx[r];
        float4 tv = *(const float4*)(T4 + b * 128 + c0);
        acc[i][0] += tv.x; acc[i][1] += tv.y; acc[i][2] += tv.z; acc[i][3] += tv.w;
    }
    // normalize + relu: x = max(fused*s + t, 0)
    float4 sc = *(const float4*)(ws + WS_S + c0);
    float4 tb = *(const float4*)(ws + WS_T + c0);
#pragma unroll
    for (int i = 0; i < 8; ++i) {
        acc[i][0] = fmaxf(acc[i][0] * sc.x + tb.x, 0.f);
        acc[i][1] = fmaxf(acc[i][1] * sc.y + tb.y, 0.f);
        acc[i][2] = fmaxf(acc[i][2] * sc.z + tb.z, 0.f);
        acc[i][3] = fmaxf(acc[i][3] * sc.w + tb.w, 0.f);
    }
    // head weights for this thread's 4 columns
    float wh[4][9];
#pragma unroll
    for (int jj = 0; jj < 4; ++jj)
#pragma unroll
        for (int j = 0; j < 9; ++j) wh[jj][j] = ws[WS_WH + (c0 + jj) * 9 + j];
    float bh[9];
#pragma unroll
    for (int j = 0; j < 9; ++j) bh[j] = ws[WS_BH + j];

#pragma unroll
    for (int i = 0; i < 8; ++i) {
        float p[9];
#pragma unroll
        for (int j = 0; j < 9; ++j) p[j] = 0.f;
#pragma unroll
        for (int jj = 0; jj < 4; ++jj) {
            float xv = acc[i][jj];
#pragma unroll
            for (int j = 0; j < 9; ++j) p[j] += xv * wh[jj][j];
        }
        // reduce across the 32 tx lanes (stay within the 32-lane half of the wave)
#pragma unroll
        for (int m = 1; m <= 16; m <<= 1)
#pragma unroll
            for (int j = 0; j < 9; ++j) p[j] += __shfl_xor(p[j], m);
        if ((tid & 31) == 0) {
            int r = r0 + ty * 8 + i;
            float* o = out + (size_t)r * 9;
            o[0] = p[0] + bh[0];
            o[1] = p[1] + bh[1];
            o[2] = p[2] + bh[2];
            o[3] = expf(p[3] + bh[3]);
            o[4] = expf(p[4] + bh[4]);
            o[5] = expf(p[5] + bh[5]);
            o[6] = p[6] + bh[6];
            o[7] = p[7] + bh[7];
            o[8] = p[8] + bh[8];
        }
    }
}

// ---------------- kth: per box, 33rd smallest distance among same-level points ----------------
__global__ __launch_bounds__(256) void kth_kernel(const float* __restrict__ p0,
                                                  const float* __restrict__ p1,
                                                  const float* __restrict__ boxes,
                                                  const int* __restrict__ glabels,
                                                  float* __restrict__ ws)
{
    const int j = blockIdx.x;
    const int tid = threadIdx.x;
    const float cx = boxes[j * 7 + 0], cy = boxes[j * 7 + 1], cz = boxes[j * 7 + 2];
    const int lvl = glabels[j];               // LABEL2LEVEL is identity
    const float* pts = (lvl == 0) ? p0 : p1;
    const int M = (lvl == 0) ? NL0 : NL1;

    float tk[33];
#pragma unroll
    for (int u = 0; u < 33; ++u) tk[u] = FMAXV;

    for (int i = tid; i < M; i += 256) {
        float dx = __fsub_rn(pts[i * 3 + 0], cx);
        float dy = __fsub_rn(pts[i * 3 + 1], cy);
        float dz = __fsub_rn(pts[i * 3 + 2], cz);
        float d2 = __fadd_rn(__fadd_rn(__fmul_rn(dx, dx), __fmul_rn(dy, dy)), __fmul_rn(dz, dz));
        if (d2 < tk[32]) {
            float v = d2;
#pragma unroll
            for (int u = 0; u < 33; ++u) {
                float cur = tk[u];
                float nv = fminf(v, cur);
                v = fmaxf(v, cur);
                tk[u] = nv;
            }
        }
    }

    // exact 33rd-smallest via bit-pattern binary search (positive floats: uint order == float order)
    __shared__ int sred[4];
    unsigned lo = 0u, hi = __float_as_uint(FMAXV);
    for (int it = 0; it < 32; ++it) {
        unsigned mid = lo + ((hi - lo) >> 1);
        float midf = __uint_as_float(mid);
        int cnt = 0;
#pragma unroll
        for (int u = 0; u < 33; ++u) cnt += (tk[u] <= midf) ? 1 : 0;
#pragma unroll
        for (int m = 32; m >= 1; m >>= 1) cnt += __shfl_xor(cnt, m);
        if ((tid & 63) == 0) sred[tid >> 6] = cnt;
        __syncthreads();
        int total = sred[0] + sred[1] + sred[2] + sred[3];
        if (total >= 33) hi = mid; else lo = mid + 1;
        __syncthreads();
    }
    if (tid == 0) ws[WS_KTH + j] = __uint_as_float(hi);
}

// ---------------- assign: per point, raw argmin + gated argmin ----------------
__global__ __launch_bounds__(256) void assign_kernel(const float* __restrict__ p0,
                                                     const float* __restrict__ p1,
                                                     const float* __restrict__ boxes,
                                                     const int* __restrict__ glabels,
                                                     const float* __restrict__ ws,
                                                     float* __restrict__ out)
{
    __shared__ float cxa[128], cya[128], cza[128], kva[128];
    __shared__ int lva[128];
    int tid = threadIdx.x;
    if (tid < 128) {
        cxa[tid] = boxes[tid * 7 + 0];
        cya[tid] = boxes[tid * 7 + 1];
        cza[tid] = boxes[tid * 7 + 2];
        kva[tid] = ws[WS_KTH + tid];
        lva[tid] = glabels[tid];
    }
    __syncthreads();
    int i = blockIdx.x * 256 + tid;
    if (i >= N_TOT) return;
    int lvl = (i < NL0) ? 0 : 1;
    const float* p = (lvl == 0) ? (p0 + (size_t)i * 3) : (p1 + (size_t)(i - NL0) * 3);
    float px = p[0], py = p[1], pz = p[2];
    float bestA = FMAXV; int jA = 0;
    float bestG = FMAXV; int jG = -1;
    for (int j = 0; j < 128; ++j) {
        float dx = __fsub_rn(px, cxa[j]);
        float dy = __fsub_rn(py, cya[j]);
        float dz = __fsub_rn(pz, cza[j]);
        float d2 = __fadd_rn(__fadd_rn(__fmul_rn(dx, dx), __fmul_rn(dy, dy)), __fmul_rn(dz, dz));
        if (d2 < bestA) { bestA = d2; jA = j; }
        bool ok = (lva[j] == lvl) && (d2 < kva[j]);
        if (ok && d2 < bestG) { bestG = d2; jG = j; }
    }
    int res = (jG >= 0 && jG == jA) ? jG : -1;
    out[(size_t)9 * N_TOT + i] = (float)res;
}

extern "C" void kernel_launch(void* const* d_in, const int* in_sizes, int n_in,
                              void* d_out, int out_size, void* d_ws, size_t ws_size,
                              hipStream_t stream)
{
    const float* backbone = (const float*)d_in[0];
    const float* text     = (const float*)d_in[1];
    const float* Wf       = (const float*)d_in[2];
    const float* bfuse    = (const float*)d_in[3];
    const float* gamma    = (const float*)d_in[4];
    const float* beta     = (const float*)d_in[5];
    const float* Wbbox    = (const float*)d_in[6];
    const float* bbbox    = (const float*)d_in[7];
    const float* Wcls     = (const float*)d_in[8];
    const float* bcls     = (const float*)d_in[9];
    const float* p0       = (const float*)d_in[10];
    const float* p1       = (const float*)d_in[11];
    const int*   bidx     = (const int*)d_in[12];
    const int*   glab     = (const int*)d_in[13];
    const float* boxes    = (const float*)d_in[14];
    float* out = (float*)d_out;
    float* ws  = (float*)d_ws;

    prep_kernel<<<1, 256, 0, stream>>>(text, Wf, bfuse, Wbbox, bbbox, Wcls, bcls, ws);
    gemm_stats_kernel<<<N_TOT / 64, 256, 0, stream>>>(backbone, Wf, bidx, ws);
    finalize_kernel<<<1, 128, 0, stream>>>(gamma, beta, ws, N_TOT);
    heads_kernel<<<N_TOT / 64, 256, 0, stream>>>(backbone, Wf, bidx, ws, out);
    kth_kernel<<<NBOX, 256, 0, stream>>>(p0, p1, boxes, glab, ws);
    assign_kernel<<<(N_TOT + 255) / 256, 256, 0, stream>>>(p0, p1, boxes, glab, ws, out);
}

// Round 3
// 377.665 us; speedup vs baseline: 1.6922x; 1.6922x over previous
//
#include <hip/hip_runtime.h>
#include <math.h>

#define N_TOT 160000
#define NL0   100000
#define NL1   60000
#define NBOX  128
#define FMAXV 1e8f
#define CAP   2048

// ws float offsets
#define WS_SUM   0
#define WS_SQ    128
#define WS_S     256
#define WS_T     384
#define WS_T4    512
#define WS_WH    1024
#define WS_BH    2176
#define WS_KTH   2192
#define WS_TB    2320
#define WS_CNT   2448   // 128 ints -> ends at 2576
#define WS_CAND  3072   // 128*2048 floats -> ends at 265216
#define WS_FUSED 524288 // float offset; cached-fused region (160000*128 floats)

// ---------------- prep: zero stats+counters, T4 = text@Wf[128:]+b_fuse, pack head weights ----------------
__global__ void prep_kernel(const float* __restrict__ text, const float* __restrict__ Wf,
                            const float* __restrict__ bfuse, const float* __restrict__ Wbbox,
                            const float* __restrict__ bbbox, const float* __restrict__ Wcls,
                            const float* __restrict__ bcls, float* __restrict__ ws)
{
    int t = threadIdx.x;
    if (t < 128) { ws[WS_SUM + t] = 0.f; ws[WS_SQ + t] = 0.f; ((int*)(ws + WS_CNT))[t] = 0; }
    for (int idx = t; idx < 512; idx += 256) {
        int b = idx >> 7, c = idx & 127;
        float acc = bfuse[c];
        for (int k = 0; k < 128; ++k) acc += text[b * 128 + k] * Wf[(128 + k) * 128 + c];
        ws[WS_T4 + idx] = acc;
    }
    for (int idx = t; idx < 1152; idx += 256) {
        int k = idx / 9, j = idx - k * 9;
        ws[WS_WH + idx] = (j < 7) ? Wbbox[k * 7 + j] : Wcls[k * 2 + (j - 7)];
    }
    if (t < 9) ws[WS_BH + t] = (t < 7) ? bbbox[t] : bcls[t - 7];
}

// ---------------- GEMM core: 64 rows/block, 256 thr: tx=col/4, ty=rowgrp ----------------
#define GEMM_BODY(A, Wf, lw, acc, r0, tx, ty, c0)                                        \
    for (int ph = 0; ph < 2; ++ph) {                                                     \
        const float4* wsrc = (const float4*)((Wf) + ph * 8192);                          \
        float4* wdst = (float4*)(lw);                                                    \
        for (int i = threadIdx.x; i < 2048; i += 256) wdst[i] = wsrc[i];                 \
        __syncthreads();                                                                 \
        for (int k4 = 0; k4 < 16; ++k4) {                                                \
            float4 a[8];                                                                 \
            _Pragma("unroll")                                                            \
            for (int i = 0; i < 8; ++i)                                                  \
                a[i] = *(const float4*)((A) + (size_t)((r0) + (ty) * 8 + i) * 128 + ph * 64 + k4 * 4); \
            _Pragma("unroll")                                                            \
            for (int kk = 0; kk < 4; ++kk) {                                             \
                float4 w = *(const float4*)((lw) + (k4 * 4 + kk) * 128 + (c0));          \
                _Pragma("unroll")                                                        \
                for (int i = 0; i < 8; ++i) {                                            \
                    float av = (kk == 0) ? a[i].x : (kk == 1) ? a[i].y : (kk == 2) ? a[i].z : a[i].w; \
                    acc[i][0] += av * w.x; acc[i][1] += av * w.y;                        \
                    acc[i][2] += av * w.z; acc[i][3] += av * w.w;                        \
                }                                                                        \
            }                                                                            \
        }                                                                                \
        __syncthreads();                                                                 \
    }

__global__ __launch_bounds__(256) void gemm_stats_kernel(const float* __restrict__ A,
                                                         const float* __restrict__ Wf,
                                                         const int* __restrict__ bidx,
                                                         float* __restrict__ ws,
                                                         float* __restrict__ fused_out)
{
    __shared__ float lw[8192];
    __shared__ float red[2048];
    const int tid = threadIdx.x;
    const int tx = tid & 31, ty = tid >> 5;
    const int r0 = blockIdx.x * 64;
    const int c0 = tx * 4;
    float acc[8][4];
#pragma unroll
    for (int i = 0; i < 8; ++i)
#pragma unroll
        for (int j = 0; j < 4; ++j) acc[i][j] = 0.f;

    GEMM_BODY(A, Wf, lw, acc, r0, tx, ty, c0)

    const float* T4 = ws + WS_T4;
#pragma unroll
    for (int i = 0; i < 8; ++i) {
        int r = r0 + ty * 8 + i;
        int b = bidx[r];
        float4 tv = *(const float4*)(T4 + b * 128 + c0);
        acc[i][0] += tv.x; acc[i][1] += tv.y; acc[i][2] += tv.z; acc[i][3] += tv.w;
    }
    if (fused_out) {
#pragma unroll
        for (int i = 0; i < 8; ++i) {
            int r = r0 + ty * 8 + i;
            float4 v = make_float4(acc[i][0], acc[i][1], acc[i][2], acc[i][3]);
            *(float4*)(fused_out + (size_t)r * 128 + c0) = v;
        }
    }
#pragma unroll
    for (int j = 0; j < 4; ++j) {
        float s = 0.f, s2 = 0.f;
#pragma unroll
        for (int i = 0; i < 8; ++i) { float v = acc[i][j]; s += v; s2 += v * v; }
        red[(c0 + j) * 8 + ty] = s;
        red[1024 + (c0 + j) * 8 + ty] = s2;
    }
    __syncthreads();
    if (tid < 128) {
        float s = 0.f, s2 = 0.f;
#pragma unroll
        for (int u = 0; u < 8; ++u) { s += red[tid * 8 + u]; s2 += red[1024 + tid * 8 + u]; }
        atomicAdd(ws + WS_SUM + tid, s);
        atomicAdd(ws + WS_SQ + tid, s2);
    }
}

__global__ void finalize_kernel(const float* __restrict__ gamma, const float* __restrict__ beta,
                                float* __restrict__ ws, int n)
{
    int c = threadIdx.x;
    if (c < 128) {
        float inv_n = 1.f / (float)n;
        float mu  = ws[WS_SUM + c] * inv_n;
        float var = ws[WS_SQ + c] * inv_n - mu * mu;
        float s = gamma[c] / sqrtf(var + 1e-5f);
        ws[WS_S + c] = s;
        ws[WS_T + c] = beta[c] - mu * s;
    }
}

// -------- epilogue shared by both heads variants: BN+ReLU, 9-col head GEMM, write out --------
__device__ __forceinline__ void heads_epilogue(float acc[8][4], const float* __restrict__ ws,
                                               float* __restrict__ out, int r0, int tx, int ty, int c0)
{
    float4 sc = *(const float4*)(ws + WS_S + c0);
    float4 tb = *(const float4*)(ws + WS_T + c0);
#pragma unroll
    for (int i = 0; i < 8; ++i) {
        acc[i][0] = fmaxf(acc[i][0] * sc.x + tb.x, 0.f);
        acc[i][1] = fmaxf(acc[i][1] * sc.y + tb.y, 0.f);
        acc[i][2] = fmaxf(acc[i][2] * sc.z + tb.z, 0.f);
        acc[i][3] = fmaxf(acc[i][3] * sc.w + tb.w, 0.f);
    }
    float wh[4][9];
#pragma unroll
    for (int jj = 0; jj < 4; ++jj)
#pragma unroll
        for (int j = 0; j < 9; ++j) wh[jj][j] = ws[WS_WH + (c0 + jj) * 9 + j];
    float bh[9];
#pragma unroll
    for (int j = 0; j < 9; ++j) bh[j] = ws[WS_BH + j];

#pragma unroll
    for (int i = 0; i < 8; ++i) {
        float p[9];
#pragma unroll
        for (int j = 0; j < 9; ++j) p[j] = 0.f;
#pragma unroll
        for (int jj = 0; jj < 4; ++jj) {
            float xv = acc[i][jj];
#pragma unroll
            for (int j = 0; j < 9; ++j) p[j] += xv * wh[jj][j];
        }
#pragma unroll
        for (int m = 1; m <= 16; m <<= 1)
#pragma unroll
            for (int j = 0; j < 9; ++j) p[j] += __shfl_xor(p[j], m);
        if (tx == 0) {
            int r = r0 + ty * 8 + i;
            float* o = out + (size_t)r * 9;
            o[0] = p[0] + bh[0];
            o[1] = p[1] + bh[1];
            o[2] = p[2] + bh[2];
            o[3] = expf(p[3] + bh[3]);
            o[4] = expf(p[4] + bh[4]);
            o[5] = expf(p[5] + bh[5]);
            o[6] = p[6] + bh[6];
            o[7] = p[7] + bh[7];
            o[8] = p[8] + bh[8];
        }
    }
}

// heads from cached fused (memory-bound path)
__global__ __launch_bounds__(256) void heads_cached_kernel(const float* __restrict__ fused,
                                                           const float* __restrict__ ws,
                                                           float* __restrict__ out)
{
    const int tid = threadIdx.x;
    const int tx = tid & 31, ty = tid >> 5;
    const int r0 = blockIdx.x * 64;
    const int c0 = tx * 4;
    float acc[8][4];
#pragma unroll
    for (int i = 0; i < 8; ++i) {
        float4 v = *(const float4*)(fused + (size_t)(r0 + ty * 8 + i) * 128 + c0);
        acc[i][0] = v.x; acc[i][1] = v.y; acc[i][2] = v.z; acc[i][3] = v.w;
    }
    heads_epilogue(acc, ws, out, r0, tx, ty, c0);
}

// heads with GEMM recompute (fallback when ws too small)
__global__ __launch_bounds__(256) void heads_kernel(const float* __restrict__ A,
                                                    const float* __restrict__ Wf,
                                                    const int* __restrict__ bidx,
                                                    const float* __restrict__ ws,
                                                    float* __restrict__ out)
{
    __shared__ float lw[8192];
    const int tid = threadIdx.x;
    const int tx = tid & 31, ty = tid >> 5;
    const int r0 = blockIdx.x * 64;
    const int c0 = tx * 4;
    float acc[8][4];
#pragma unroll
    for (int i = 0; i < 8; ++i)
#pragma unroll
        for (int j = 0; j < 4; ++j) acc[i][j] = 0.f;

    GEMM_BODY(A, Wf, lw, acc, r0, tx, ty, c0)

    const float* T4 = ws + WS_T4;
#pragma unroll
    for (int i = 0; i < 8; ++i) {
        int r = r0 + ty * 8 + i;
        int b = bidx[r];
        float4 tv = *(const float4*)(T4 + b * 128 + c0);
        acc[i][0] += tv.x; acc[i][1] += tv.y; acc[i][2] += tv.z; acc[i][3] += tv.w;
    }
    heads_epilogue(acc, ws, out, r0, tx, ty, c0);
}

// ---------------- kth phase 1: per-box upper bound T = 33rd smallest of 1024 thread-minima ----------------
__global__ __launch_bounds__(1024) void bound_kernel(const float* __restrict__ p0,
                                                     const float* __restrict__ p1,
                                                     const float* __restrict__ boxes,
                                                     const int* __restrict__ glabels,
                                                     float* __restrict__ ws)
{
    const int j = blockIdx.x;
    const int tid = threadIdx.x;
    const float cx = boxes[j * 7 + 0], cy = boxes[j * 7 + 1], cz = boxes[j * 7 + 2];
    const int lvl = glabels[j];
    const float* pts = (lvl == 0) ? p0 : p1;
    const int M = (lvl == 0) ? NL0 : NL1;

    float m0 = FMAXV, m1 = FMAXV;
    for (int i = tid; i < M; i += 2048) {
        {
            float dx = __fsub_rn(pts[i * 3 + 0], cx);
            float dy = __fsub_rn(pts[i * 3 + 1], cy);
            float dz = __fsub_rn(pts[i * 3 + 2], cz);
            float d2 = __fadd_rn(__fadd_rn(__fmul_rn(dx, dx), __fmul_rn(dy, dy)), __fmul_rn(dz, dz));
            m0 = fminf(m0, d2);
        }
        int i2 = i + 1024;
        if (i2 < M) {
            float dx = __fsub_rn(pts[i2 * 3 + 0], cx);
            float dy = __fsub_rn(pts[i2 * 3 + 1], cy);
            float dz = __fsub_rn(pts[i2 * 3 + 2], cz);
            float d2 = __fadd_rn(__fadd_rn(__fmul_rn(dx, dx), __fmul_rn(dy, dy)), __fmul_rn(dz, dz));
            m1 = fminf(m1, d2);
        }
    }
    float m = fminf(m0, m1);

    // exact 33rd smallest of the 1024 minima via bit-pattern binary search
    __shared__ int wsum[16];
    unsigned lo = 0u, hi = __float_as_uint(FMAXV);
    for (int it = 0; it < 32; ++it) {
        unsigned mid = lo + ((hi - lo) >> 1);
        float midf = __uint_as_float(mid);
        unsigned long long b = __ballot(m <= midf);
        if ((tid & 63) == 0) wsum[tid >> 6] = __popcll(b);
        __syncthreads();
        int total = 0;
#pragma unroll
        for (int w = 0; w < 16; ++w) total += wsum[w];
        if (total >= 33) hi = mid; else lo = mid + 1;
        __syncthreads();
    }
    if (tid == 0) ws[WS_TB + j] = __uint_as_float(hi);
}

// ---------------- kth phase 2: collect ALL d2 <= T_j per box ----------------
__global__ __launch_bounds__(256) void collect_kernel(const float* __restrict__ p0,
                                                      const float* __restrict__ p1,
                                                      const float* __restrict__ boxes,
                                                      const int* __restrict__ glabels,
                                                      float* __restrict__ ws)
{
    const int j = blockIdx.x;
    const int slice = blockIdx.y, nslice = gridDim.y;
    const int tid = threadIdx.x;
    const float cx = boxes[j * 7 + 0], cy = boxes[j * 7 + 1], cz = boxes[j * 7 + 2];
    const int lvl = glabels[j];
    const float* pts = (lvl == 0) ? p0 : p1;
    const int M = (lvl == 0) ? NL0 : NL1;
    const float T = ws[WS_TB + j];
    int* cnt = (int*)(ws + WS_CNT) + j;
    float* cand = ws + WS_CAND + (size_t)j * CAP;

    const int chunk = (M + nslice - 1) / nslice;
    const int i0 = slice * chunk;
    const int i1 = min(M, i0 + chunk);
    for (int i = i0 + tid; i < i1; i += 256) {
        float dx = __fsub_rn(pts[i * 3 + 0], cx);
        float dy = __fsub_rn(pts[i * 3 + 1], cy);
        float dz = __fsub_rn(pts[i * 3 + 2], cz);
        float d2 = __fadd_rn(__fadd_rn(__fmul_rn(dx, dx), __fmul_rn(dy, dy)), __fmul_rn(dz, dz));
        if (d2 <= T) {
            int idx = atomicAdd(cnt, 1);
            if (idx < CAP) cand[idx] = d2;
        }
    }
}

// ---------------- kth phase 3: exact rank-33 over collected candidates ----------------
__global__ __launch_bounds__(256) void select_kernel(float* __restrict__ ws)
{
    const int j = blockIdx.x;
    const int tid = threadIdx.x;
    int n = ((int*)(ws + WS_CNT))[j];
    if (n > CAP) n = CAP;
    const float* cand = ws + WS_CAND + (size_t)j * CAP;
    float v[CAP / 256];
#pragma unroll
    for (int u = 0; u < CAP / 256; ++u) {
        int t = tid + u * 256;
        v[u] = (t < n) ? cand[t] : FMAXV;
    }
    __shared__ int wsum[4];
    unsigned lo = 0u, hi = __float_as_uint(FMAXV);
    for (int it = 0; it < 32; ++it) {
        unsigned mid = lo + ((hi - lo) >> 1);
        float midf = __uint_as_float(mid);
        int c = 0;
#pragma unroll
        for (int u = 0; u < CAP / 256; ++u) c += (v[u] <= midf) ? 1 : 0;
#pragma unroll
        for (int m = 32; m >= 1; m >>= 1) c += __shfl_xor(c, m);
        if ((tid & 63) == 0) wsum[tid >> 6] = c;
        __syncthreads();
        int total = wsum[0] + wsum[1] + wsum[2] + wsum[3];
        if (total >= 33) hi = mid; else lo = mid + 1;
        __syncthreads();
    }
    if (tid == 0) ws[WS_KTH + j] = __uint_as_float(hi);
}

// ---------------- assign: per point, raw argmin + gated argmin ----------------
__global__ __launch_bounds__(256) void assign_kernel(const float* __restrict__ p0,
                                                     const float* __restrict__ p1,
                                                     const float* __restrict__ boxes,
                                                     const int* __restrict__ glabels,
                                                     const float* __restrict__ ws,
                                                     float* __restrict__ out)
{
    __shared__ float cxa[128], cya[128], cza[128], kva[128];
    __shared__ int lva[128];
    int tid = threadIdx.x;
    if (tid < 128) {
        cxa[tid] = boxes[tid * 7 + 0];
        cya[tid] = boxes[tid * 7 + 1];
        cza[tid] = boxes[tid * 7 + 2];
        kva[tid] = ws[WS_KTH + tid];
        lva[tid] = glabels[tid];
    }
    __syncthreads();
    int i = blockIdx.x * 256 + tid;
    if (i >= N_TOT) return;
    int lvl = (i < NL0) ? 0 : 1;
    const float* p = (lvl == 0) ? (p0 + (size_t)i * 3) : (p1 + (size_t)(i - NL0) * 3);
    float px = p[0], py = p[1], pz = p[2];
    float bestA = FMAXV; int jA = 0;
    float bestG = FMAXV; int jG = -1;
    for (int j = 0; j < 128; ++j) {
        float dx = __fsub_rn(px, cxa[j]);
        float dy = __fsub_rn(py, cya[j]);
        float dz = __fsub_rn(pz, cza[j]);
        float d2 = __fadd_rn(__fadd_rn(__fmul_rn(dx, dx), __fmul_rn(dy, dy)), __fmul_rn(dz, dz));
        if (d2 < bestA) { bestA = d2; jA = j; }
        bool ok = (lva[j] == lvl) && (d2 < kva[j]);
        if (ok && d2 < bestG) { bestG = d2; jG = j; }
    }
    int res = (jG >= 0 && jG == jA) ? jG : -1;
    out[(size_t)9 * N_TOT + i] = (float)res;
}

extern "C" void kernel_launch(void* const* d_in, const int* in_sizes, int n_in,
                              void* d_out, int out_size, void* d_ws, size_t ws_size,
                              hipStream_t stream)
{
    const float* backbone = (const float*)d_in[0];
    const float* text     = (const float*)d_in[1];
    const float* Wf       = (const float*)d_in[2];
    const float* bfuse    = (const float*)d_in[3];
    const float* gamma    = (const float*)d_in[4];
    const float* beta     = (const float*)d_in[5];
    const float* Wbbox    = (const float*)d_in[6];
    const float* bbbox    = (const float*)d_in[7];
    const float* Wcls     = (const float*)d_in[8];
    const float* bcls     = (const float*)d_in[9];
    const float* p0       = (const float*)d_in[10];
    const float* p1       = (const float*)d_in[11];
    const int*   bidx     = (const int*)d_in[12];
    const int*   glab     = (const int*)d_in[13];
    const float* boxes    = (const float*)d_in[14];
    float* out = (float*)d_out;
    float* ws  = (float*)d_ws;

    const size_t need = ((size_t)WS_FUSED + (size_t)N_TOT * 128) * sizeof(float);
    const bool cache_fused = (ws_size >= need);
    float* fused = cache_fused ? (ws + WS_FUSED) : nullptr;

    prep_kernel<<<1, 256, 0, stream>>>(text, Wf, bfuse, Wbbox, bbbox, Wcls, bcls, ws);
    bound_kernel<<<NBOX, 1024, 0, stream>>>(p0, p1, boxes, glab, ws);
    collect_kernel<<<dim3(NBOX, 8), 256, 0, stream>>>(p0, p1, boxes, glab, ws);
    select_kernel<<<NBOX, 256, 0, stream>>>(ws);
    gemm_stats_kernel<<<N_TOT / 64, 256, 0, stream>>>(backbone, Wf, bidx, ws, fused);
    finalize_kernel<<<1, 128, 0, stream>>>(gamma, beta, ws, N_TOT);
    if (cache_fused)
        heads_cached_kernel<<<N_TOT / 64, 256, 0, stream>>>(fused, ws, out);
    else
        heads_kernel<<<N_TOT / 64, 256, 0, stream>>>(backbone, Wf, bidx, ws, out);
    assign_kernel<<<(N_TOT + 255) / 256, 256, 0, stream>>>(p0, p1, boxes, glab, ws, out);
}